// Round 4
// baseline (94.745 us; speedup 1.0000x reference)
//
#include <hip/hip_runtime.h>

typedef unsigned short u16;
typedef __attribute__((ext_vector_type(8))) __bf16 bf16x8;
typedef __attribute__((ext_vector_type(8))) unsigned short u16x8;
typedef __attribute__((ext_vector_type(4))) float f32x4;
typedef __attribute__((ext_vector_type(16))) float f32x16;

__device__ __forceinline__ u16 f2bf(float f) {
  unsigned u = __builtin_bit_cast(unsigned, f);
  unsigned r = u + 0x7fffu + ((u >> 16) & 1u);
  return (u16)(r >> 16);
}

__device__ __forceinline__ float wave_sum(float v) {
#pragma unroll
  for (int o = 32; o; o >>= 1) v += __shfl_xor(v, o, 64);
  return v;
}

__device__ __forceinline__ bf16x8 bzero() {
  bf16x8 z;
#pragma unroll
  for (int i = 0; i < 8; ++i) z[i] = (__bf16)0.0f;
  return z;
}

// ===== K1: fused xin-build (blocks 0..255) + plane sums (blocks 256..1279) =====
// xin layout: [b][h][cg(16)][px(64)][ch(32)] bf16 (per-(b,h) slab = 32768 u16)
__global__ void k_xin_plane(const float* __restrict__ tgt, const float* __restrict__ prev,
                            const float* __restrict__ src,
                            u16* __restrict__ xin, float* __restrict__ ssum) {
  __shared__ u16 lt[256 * 66];
  int tid = threadIdx.x;
  if (blockIdx.x >= 256) {              // ---- plane sum of source_enc ----
    int plane = blockIdx.x - 256;       // 0..1023
    const float* p = src + (size_t)plane * 4096;
    float s = 0.f;
#pragma unroll
    for (int i = 0; i < 4; ++i) {
      f32x4 v = *(const f32x4*)(p + (i * 256 + tid) * 4);
      s += v[0] + v[1] + v[2] + v[3];
    }
    s = wave_sum(s);
    float* red = (float*)lt;
    if ((tid & 63) == 0) red[tid >> 6] = s;
    __syncthreads();
    if (tid == 0) ssum[plane] = red[0] + red[1] + red[2] + red[3];
    return;
  }
  int b = blockIdx.x >> 6, h = blockIdx.x & 63;
  const float* tp = tgt + ((size_t)(b * 256) * 64 + h) * 64;
  u16* xp = xin + (size_t)(b * 64 + h) * 32768;
  // phase A: target rows -> LDS [c][w]
  for (int it = 0; it < 16; ++it) {
    int fi = it * 256 + tid;
    int c = fi >> 4, w4 = fi & 15;
    f32x4 v = *(const f32x4*)(tp + (size_t)c * 4096 + w4 * 4);
    int base = c * 66 + w4 * 4;
    lt[base] = f2bf(v[0]); lt[base + 1] = f2bf(v[1]);
    lt[base + 2] = f2bf(v[2]); lt[base + 3] = f2bf(v[3]);
  }
  __syncthreads();
  // write channels 0..255 (cg 0..7)
  for (int it = 0; it < 8; ++it) {
    int i = it * 256 + tid;
    int c8 = i & 31, w = i >> 5;
    u16x8 v;
#pragma unroll
    for (int k = 0; k < 8; ++k) v[k] = lt[(c8 * 8 + k) * 66 + w];
    int cg = c8 >> 2, sub = c8 & 3;
    *(u16x8*)(xp + ((size_t)cg * 64 + w) * 32 + sub * 8) = v;
  }
  __syncthreads();
  // phase B: prev upsample -> LDS [cc][w]
  const float* pp = prev + ((size_t)(b * 256) * 32 + (h >> 1)) * 32;
  for (int it = 0; it < 8; ++it) {
    int pi = it * 256 + tid;
    int cc = pi >> 3, wq = pi & 7;
    f32x4 v = *(const f32x4*)(pp + (size_t)cc * 1024 + wq * 4);
    int base = cc * 66 + wq * 8;
    u16 b0 = f2bf(v[0]), b1 = f2bf(v[1]), b2 = f2bf(v[2]), b3 = f2bf(v[3]);
    lt[base] = b0; lt[base + 1] = b0; lt[base + 2] = b1; lt[base + 3] = b1;
    lt[base + 4] = b2; lt[base + 5] = b2; lt[base + 6] = b3; lt[base + 7] = b3;
  }
  __syncthreads();
  // write channels 256..511 (cg 8..15)
  for (int it = 0; it < 8; ++it) {
    int i = it * 256 + tid;
    int c8 = i & 31, w = i >> 5;
    u16x8 v;
#pragma unroll
    for (int k = 0; k < 8; ++k) v[k] = lt[(c8 * 8 + k) * 66 + w];
    int cg = 8 + (c8 >> 2), sub = c8 & 3;
    *(u16x8*)(xp + ((size_t)cg * 64 + w) * 32 + sub * 8) = v;
  }
}

// ===== K2: Mt rows (blocks 0..255, G folded via E=A2@Wk) + dvec chain (block 256) =====
__global__ void k_mt_vec(const float* __restrict__ ssum,
                         const float* __restrict__ qw, const float* __restrict__ qb,
                         const float* __restrict__ kw, const float* __restrict__ kb,
                         const float* __restrict__ lw, const float* __restrict__ lb,
                         const float* __restrict__ aw, const float* __restrict__ ab,
                         const float* __restrict__ gamma,
                         float* __restrict__ dvec, float* __restrict__ Mt) {
  int t = threadIdx.x;
  if (blockIdx.x < 256) {
    __shared__ float E[32];
    int o = blockIdx.x;
    if (t < 32) {
      float s = 0.f;
      for (int o2 = 0; o2 < 32; ++o2) s += aw[o * 288 + 256 + o2] * lw[o2 * 64 + t];
      E[t] = s;
    }
    __syncthreads();
    int c2 = t;
    float s = 0.f;
    for (int a = 0; a < 32; ++a) s += E[a] * kw[a * 256 + c2];
    Mt[o * 256 + c2] = gamma[0] * (aw[o * 288 + c2] + 4096.f * s) + (o == c2 ? 1.f : 0.f);
    return;
  }
  __shared__ float qs_l[128], amap_l[128];
  if (t < 128) {
    int b = t >> 5, o = t & 31;
    float s = 4096.f * qb[o];
    for (int c = 0; c < 256; ++c) s += qw[o * 256 + c] * ssum[b * 256 + c];
    qs_l[t] = s;
  }
  __syncthreads();
  if (t < 128) {
    int b = t >> 5, o2 = t & 31;
    float s = 0.f, kt = 0.f;
    for (int o = 0; o < 32; ++o) {
      s += lw[o2 * 64 + 32 + o] * qs_l[b * 32 + o];
      kt += lw[o2 * 64 + o] * kb[o];
    }
    amap_l[t] = 4096.f * (kt + lb[o2]) + s;
  }
  __syncthreads();
  float g = gamma[0];
  for (int i = t; i < 1024; i += 256) {
    int b = i >> 8, c = i & 255;
    float s = ab[c];
    for (int o2 = 0; o2 < 32; ++o2) s += aw[c * 288 + 256 + o2] * amap_l[b * 32 + o2];
    dvec[i] = g * s;
  }
}

// ===== K3: folded conv weights w3 (bf16, 32x32-fragment-major) + cd2 =====
// w3 idx(tap,cg,MT,ks,kh,m,j) = ((((tap*16+cg)*4+MT)*2+ks)*2+kh)*256 + m*8 + j
//   for oc = MT*32+m, channel cf = cg*32 + ks*16 + kh*8 + j
__global__ void k_w3(const float* __restrict__ cw, const float* __restrict__ Mt,
                     const float* __restrict__ dvec, u16* __restrict__ w3,
                     float* __restrict__ cd2) {
  __shared__ float cwl[8 * 512];
  __shared__ float part[512];
  int blk = blockIdx.x;                 // 144 = 9*16
  int tap = blk >> 4, ocg = blk & 15;
  int tid = threadIdx.x;                // 512 threads
  for (int e = tid; e < 4096; e += 512) {
    int oc = e >> 9, c = e & 511;
    cwl[e] = cw[(size_t)((ocg * 8 + oc) * 512 + c) * 9 + tap];
  }
  __syncthreads();
  int wv = tid >> 6, l = tid & 63;
  int c2 = l * 4;
  f32x4 acc = {0.f, 0.f, 0.f, 0.f};
  for (int c = 0; c < 256; ++c) {
    float wc = cwl[wv * 512 + c];
    f32x4 m = *(const f32x4*)(Mt + c * 256 + c2);
#pragma unroll
    for (int j = 0; j < 4; ++j) acc[j] += wc * m[j];
  }
  int ocf = ocg * 8 + wv;
  int MT = ocf >> 5, m = ocf & 31;
#pragma unroll
  for (int j2 = 0; j2 < 4; ++j2) {
    int cf = c2 + j2;
    int cg = cf >> 5, ks = (cf >> 4) & 1, kh = (cf >> 3) & 1, j = cf & 7;
    w3[((((tap * 16 + cg) * 4 + MT) * 2 + ks) * 2 + kh) * 256 + m * 8 + j] = f2bf(acc[j2]);
    cf = 256 + c2 + j2;
    cg = cf >> 5; ks = (cf >> 4) & 1; kh = (cf >> 3) & 1; j = cf & 7;
    w3[((((tap * 16 + cg) * 4 + MT) * 2 + ks) * 2 + kh) * 256 + m * 8 + j] = f2bf(cwl[wv * 512 + cf]);
  }
  // cd2[(b*128+oc)*9+tap] = sum_{c<256} cw[oc][c][tap] * dvec[b][c]
  {
    int b = tid >> 7, oc = (tid >> 4) & 7, cp = tid & 15;
    float s = 0.f;
#pragma unroll
    for (int i = 0; i < 16; ++i) s += cwl[oc * 512 + cp * 16 + i] * dvec[b * 256 + cp * 16 + i];
    part[tid] = s;
  }
  __syncthreads();
  if (tid < 32) {
    int b = tid >> 3, oc = tid & 7;
    float s = 0.f;
#pragma unroll
    for (int cp = 0; cp < 16; ++cp) s += part[b * 128 + oc * 16 + cp];
    cd2[(size_t)(b * 128 + ocg * 8 + oc) * 9 + tap] = s;
  }
}

// ===== K4: conv, 32x32x16 MFMA. block=(b,hp,mh): M64 oc x 64 px x 2 rows. =====
// 8 waves = 4 K-teams x 2 row-waves; wave tile M64 x N64, acc = 4x f32x16.
// LDS 64KB: stage[4 teams][4 rows][64 px][32 ch] u16, T14 single-buffered.
__global__ __launch_bounds__(512, 2) void k_conv(const u16* __restrict__ xin,
                                                 const u16* __restrict__ w3,
                                                 const float* __restrict__ cd2,
                                                 float* __restrict__ out) {
  __shared__ u16 lds[32768];
  int bid = blockIdx.x;
  int b = bid >> 6, hp = (bid >> 1) & 31, mh = bid & 1;
  int h0 = hp * 2;
  int tid = threadIdx.x, l = tid & 63, wv = tid >> 6;
  int team = wv >> 1, rw = wv & 1;
  int ml = l & 31, kh = l >> 5;

  u16x8 st[8]; bool sdo[2];
  auto STAGE_LOAD = [&](int k) {
#pragma unroll
    for (int q = 0; q < 2; ++q) {
      int c = tid * 2 + q;
      int steam = c >> 8, srow = (c >> 6) & 3, spx = c & 63;
      int grow = h0 - 1 + srow;
      bool ok = ((unsigned)grow < 64u);
      sdo[q] = ok;
      const u16* gp = xin + ((((size_t)(b * 64) + grow) * 16 + steam * 4 + k) * 64 + spx) * 32;
#pragma unroll
      for (int g = 0; g < 4; ++g)
        if (ok) st[q * 4 + g] = *(const u16x8*)(gp + g * 8);
    }
  };
  auto STAGE_WRITE = [&]() {
    u16x8 zz;
#pragma unroll
    for (int i = 0; i < 8; ++i) zz[i] = 0;
#pragma unroll
    for (int q = 0; q < 2; ++q) {
      int c = tid * 2 + q;
      int steam = c >> 8, srow = (c >> 6) & 3, spx = c & 63;
      int base = steam * 8192 + srow * 2048 + spx * 32;
      int s3 = (spx >> 1) & 3;
#pragma unroll
      for (int g = 0; g < 4; ++g)
        *(u16x8*)(lds + base + (g ^ s3) * 8) = sdo[q] ? st[q * 4 + g] : zz;
    }
  };

  f32x16 acc[2][2];
#pragma unroll
  for (int mt = 0; mt < 2; ++mt)
#pragma unroll
    for (int nf = 0; nf < 2; ++nf)
#pragma unroll
      for (int j = 0; j < 16; ++j) acc[mt][nf][j] = 0.f;

  STAGE_LOAD(0);
  STAGE_WRITE();
  __syncthreads();
  for (int k = 0; k < 4; ++k) {
    if (k < 3) STAGE_LOAD(k + 1);
    const int cg = team * 4 + k;
    const u16* wt = w3 + (size_t)cg * 4096 + mh * 2048 + kh * 256 + ml * 8;
    const u16* Lt = lds + team * 8192 + rw * 2048;
#pragma unroll
    for (int t = 0; t < 9; ++t) {
      const int dy = t / 3, dx = t % 3;
#pragma unroll
      for (int ks = 0; ks < 2; ++ks) {
        bf16x8 a0 = *(const bf16x8*)(wt + t * 65536 + ks * 512);
        bf16x8 a1 = *(const bf16x8*)(wt + t * 65536 + ks * 512 + 1024);
        bf16x8 b0, b1;
#pragma unroll
        for (int nf = 0; nf < 2; ++nf) {
          int sx = nf * 32 + ml + dx - 1;
          bf16x8 z = bzero();
          if ((unsigned)sx < 64u) {
            int p = (ks * 2 + kh) ^ ((sx >> 1) & 3);
            z = *(const bf16x8*)(Lt + dy * 2048 + sx * 32 + p * 8);
          }
          if (nf == 0) b0 = z; else b1 = z;
        }
        acc[0][0] = __builtin_amdgcn_mfma_f32_32x32x16_bf16(a0, b0, acc[0][0], 0, 0, 0);
        acc[0][1] = __builtin_amdgcn_mfma_f32_32x32x16_bf16(a0, b1, acc[0][1], 0, 0, 0);
        acc[1][0] = __builtin_amdgcn_mfma_f32_32x32x16_bf16(a1, b0, acc[1][0], 0, 0, 0);
        acc[1][1] = __builtin_amdgcn_mfma_f32_32x32x16_bf16(a1, b1, acc[1][1], 0, 0, 0);
      }
    }
    __syncthreads();
    if (k < 3) { STAGE_WRITE(); __syncthreads(); }
  }

  // ---- cross-team reduction (2 passes), regions of 16KB in the 64KB LDS ----
  float* red = (float*)lds;
  auto DUMP = [&](int region) {
#pragma unroll
    for (int mt = 0; mt < 2; ++mt)
#pragma unroll
      for (int nf = 0; nf < 2; ++nf)
#pragma unroll
        for (int j4 = 0; j4 < 4; ++j4) {
          f32x4 v = {acc[mt][nf][j4 * 4], acc[mt][nf][j4 * 4 + 1],
                     acc[mt][nf][j4 * 4 + 2], acc[mt][nf][j4 * 4 + 3]};
          *(f32x4*)(red + region * 4096 + (mt * 2 + nf) * 1024 + j4 * 256 + l * 4) = v;
        }
  };
  auto ADD = [&](int region) {
#pragma unroll
    for (int mt = 0; mt < 2; ++mt)
#pragma unroll
      for (int nf = 0; nf < 2; ++nf)
#pragma unroll
        for (int j4 = 0; j4 < 4; ++j4) {
          f32x4 v = *(const f32x4*)(red + region * 4096 + (mt * 2 + nf) * 1024 + j4 * 256 + l * 4);
#pragma unroll
          for (int jj = 0; jj < 4; ++jj) acc[mt][nf][j4 * 4 + jj] += v[jj];
        }
  };
  if (team >= 2) DUMP((team - 2) * 2 + rw);
  __syncthreads();
  if (team == 0) ADD(rw);
  if (team == 1) ADD(2 + rw);
  __syncthreads();
  if (team == 1) DUMP(rw);
  __syncthreads();
  if (team == 0) ADD(rw);
  if (team != 0) return;

  // ---- epilogue: border-masked constant correction + store pre-norm y ----
  int h = h0 + rw;
  bool dy0v = (h > 0), dy2v = (h < 63);
#pragma unroll
  for (int mt = 0; mt < 2; ++mt) {
#pragma unroll
    for (int rg = 0; rg < 4; ++rg) {
#pragma unroll
      for (int j = 0; j < 4; ++j) {
        int oc = mh * 64 + mt * 32 + j + 8 * rg + 4 * kh;
        const float* cd = cd2 + (size_t)(b * 128 + oc) * 9;
        float sAll = 0.f, sL = 0.f, sR = 0.f;
#pragma unroll
        for (int dy = 0; dy < 3; ++dy) {
          bool v = (dy == 1) || (dy == 0 ? dy0v : dy2v);
          if (v) {
            sAll += cd[dy * 3] + cd[dy * 3 + 1] + cd[dy * 3 + 2];
            sL += cd[dy * 3];
            sR += cd[dy * 3 + 2];
          }
        }
#pragma unroll
        for (int nf = 0; nf < 2; ++nf) {
          int px = nf * 32 + ml;
          float corr = sAll - (px == 0 ? sL : 0.f) - (px == 63 ? sR : 0.f);
          out[((size_t)(b * 128 + oc)) * 4096 + h * 64 + px] = acc[mt][nf][rg * 4 + j] + corr;
        }
      }
    }
  }
}

// ===== K5: in-place instance norm + relu =====
__global__ void k_norm(float* __restrict__ out) {
  int plane = blockIdx.x;               // 512 = 4*128
  float* p = out + (size_t)plane * 4096;
  int t = threadIdx.x;
  f32x4 v[4];
  float s = 0.f, s2 = 0.f;
#pragma unroll
  for (int i = 0; i < 4; ++i) {
    v[i] = *(const f32x4*)(p + (i * 256 + t) * 4);
#pragma unroll
    for (int k = 0; k < 4; ++k) { s += v[i][k]; s2 += v[i][k] * v[i][k]; }
  }
  s = wave_sum(s); s2 = wave_sum(s2);
  __shared__ float rs[4], rs2[4];
  if ((t & 63) == 0) { rs[t >> 6] = s; rs2[t >> 6] = s2; }
  __syncthreads();
  float S = rs[0] + rs[1] + rs[2] + rs[3];
  float S2 = rs2[0] + rs2[1] + rs2[2] + rs2[3];
  float mean = S * (1.f / 4096.f);
  float var = S2 * (1.f / 4096.f) - mean * mean;
  float inv = rsqrtf(var + 1e-5f);
#pragma unroll
  for (int i = 0; i < 4; ++i) {
    f32x4 o;
#pragma unroll
    for (int k = 0; k < 4; ++k) {
      float y = (v[i][k] - mean) * inv;
      o[k] = y > 0.f ? y : 0.f;
    }
    *(f32x4*)(p + (i * 256 + t) * 4) = o;
  }
}

extern "C" void kernel_launch(void* const* d_in, const int* in_sizes, int n_in,
                              void* d_out, int out_size, void* d_ws, size_t ws_size,
                              hipStream_t stream) {
  const float* src    = (const float*)d_in[0];
  const float* tgt    = (const float*)d_in[1];
  const float* prev   = (const float*)d_in[2];
  const float* key_w  = (const float*)d_in[3];
  const float* key_b  = (const float*)d_in[4];
  const float* qry_w  = (const float*)d_in[5];
  const float* qry_b  = (const float*)d_in[6];
  const float* lin_w  = (const float*)d_in[7];
  const float* lin_b  = (const float*)d_in[8];
  const float* attn_w = (const float*)d_in[9];
  const float* attn_b = (const float*)d_in[10];
  const float* gamma  = (const float*)d_in[11];
  const float* conv_w = (const float*)d_in[12];
  // d_in[13] = conv_b: dropped — per-(b,oc) constant cancels under instance norm.

  char* ws = (char*)d_ws;
  size_t off = 0;
  u16*   xin  = (u16*)(ws + off);  off += 16777216;            // 4*64*64*512 bf16
  float* ssum = (float*)(ws + off); off += 4096;               // 4*256
  float* dvec = (float*)(ws + off); off += 4096;               // 4*256
  float* Mt   = (float*)(ws + off); off += 262144;             // 256*256
  float* cd2  = (float*)(ws + off); off += 18432;              // 4*128*9
  u16*   w3   = (u16*)(ws + off);  off += 1179648;             // 9*16*4*2*2*256 bf16
  float* out  = (float*)d_out;

  k_xin_plane<<<1280, 256, 0, stream>>>(tgt, prev, src, xin, ssum);
  k_mt_vec<<<257, 256, 0, stream>>>(ssum, qry_w, qry_b, key_w, key_b, lin_w, lin_b,
                                    attn_w, attn_b, gamma, dvec, Mt);
  k_w3<<<144, 512, 0, stream>>>(conv_w, Mt, dvec, w3, cd2);
  k_conv<<<256, 512, 0, stream>>>(xin, w3, cd2, out);
  k_norm<<<512, 256, 0, stream>>>(out);
}

// Round 5
// 89.498 us; speedup vs baseline: 1.0586x; 1.0586x over previous
//
#include <hip/hip_runtime.h>

typedef unsigned short u16;
typedef __attribute__((ext_vector_type(8))) __bf16 bf16x8;
typedef __attribute__((ext_vector_type(8))) unsigned short u16x8;
typedef __attribute__((ext_vector_type(4))) float f32x4;
typedef __attribute__((ext_vector_type(16))) float f32x16;

__device__ __forceinline__ u16 f2bf(float f) {
  unsigned u = __builtin_bit_cast(unsigned, f);
  unsigned r = u + 0x7fffu + ((u >> 16) & 1u);
  return (u16)(r >> 16);
}

__device__ __forceinline__ float wave_sum(float v) {
#pragma unroll
  for (int o = 32; o; o >>= 1) v += __shfl_xor(v, o, 64);
  return v;
}

__device__ __forceinline__ bf16x8 bzero() {
  bf16x8 z;
#pragma unroll
  for (int i = 0; i < 8; ++i) z[i] = (__bf16)0.0f;
  return z;
}

// async global(16B/lane) -> LDS (wave-uniform dest + lane*16)
__device__ __forceinline__ void gl2lds16(const u16* g, u16* l) {
  __builtin_amdgcn_global_load_lds(
      (const __attribute__((address_space(1))) unsigned int*)(const void*)g,
      (__attribute__((address_space(3))) unsigned int*)(void*)l, 16, 0, 0);
}

// ===== K1: xin build (blocks 0..255, no-LDS transpose) + plane sums (256..1279) =====
// xin layout: [b][h][cg(16)][px(64)][slot(4)][8ch] bf16, PRE-SWIZZLED:
//   slot s at px holds channel-octet g = s ^ ((px>>1)&3), channel = cg*32+g*8+j
__global__ void k_xin_plane(const float* __restrict__ tgt, const float* __restrict__ prev,
                            const float* __restrict__ src,
                            u16* __restrict__ xin, float* __restrict__ ssum) {
  int tid = threadIdx.x;
  if (blockIdx.x >= 256) {              // ---- plane sum of source_enc ----
    __shared__ float red[4];
    int plane = blockIdx.x - 256;       // 0..1023
    const float* p = src + (size_t)plane * 4096;
    float s = 0.f;
#pragma unroll
    for (int i = 0; i < 4; ++i) {
      f32x4 v = *(const f32x4*)(p + (i * 256 + tid) * 4);
      s += v[0] + v[1] + v[2] + v[3];
    }
    s = wave_sum(s);
    if ((tid & 63) == 0) red[tid >> 6] = s;
    __syncthreads();
    if (tid == 0) ssum[plane] = red[0] + red[1] + red[2] + red[3];
    return;
  }
  int b = blockIdx.x >> 6, h = blockIdx.x & 63;
  int wv = tid >> 6, w = tid & 63;
  u16* xp = xin + (size_t)(b * 64 + h) * 32768;
  int sw3 = (w >> 1) & 3;
  // target channels 0..255 (cg 0..7): 8 coalesced channel-row loads -> 1 store
#pragma unroll
  for (int i = 0; i < 8; ++i) {
    int c8 = wv * 8 + i;
    const float* tp = tgt + (((size_t)(b * 256 + c8 * 8)) * 64 + h) * 64 + w;
    u16x8 v;
#pragma unroll
    for (int kk = 0; kk < 8; ++kk) v[kk] = f2bf(tp[(size_t)kk * 4096]);
    int sw = (c8 & 3) ^ sw3;
    *(u16x8*)(xp + (((c8 >> 2) * 64 + w) * 4 + sw) * 8) = v;
  }
  // prev channels (upsampled) -> cg 8..15
#pragma unroll
  for (int i = 0; i < 8; ++i) {
    int po = wv * 8 + i;
    const float* pp = prev + (((size_t)(b * 256 + po * 8)) * 32 + (h >> 1)) * 32 + (w >> 1);
    u16x8 v;
#pragma unroll
    for (int kk = 0; kk < 8; ++kk) v[kk] = f2bf(pp[(size_t)kk * 1024]);
    int cg = 8 + (po >> 2), g = po & 3;
    int sw = g ^ sw3;
    *(u16x8*)(xp + ((cg * 64 + w) * 4 + sw) * 8) = v;
  }
}

// ===== K2: Mt rows (blocks 0..255, G folded via E=A2@Wk) + dvec chain (block 256) =====
__global__ void k_mt_vec(const float* __restrict__ ssum,
                         const float* __restrict__ qw, const float* __restrict__ qb,
                         const float* __restrict__ kw, const float* __restrict__ kb,
                         const float* __restrict__ lw, const float* __restrict__ lb,
                         const float* __restrict__ aw, const float* __restrict__ ab,
                         const float* __restrict__ gamma,
                         float* __restrict__ dvec, float* __restrict__ Mt) {
  int t = threadIdx.x;
  if (blockIdx.x < 256) {
    __shared__ float E[32];
    int o = blockIdx.x;
    if (t < 32) {
      float s = 0.f;
      for (int o2 = 0; o2 < 32; ++o2) s += aw[o * 288 + 256 + o2] * lw[o2 * 64 + t];
      E[t] = s;
    }
    __syncthreads();
    int c2 = t;
    float s = 0.f;
    for (int a = 0; a < 32; ++a) s += E[a] * kw[a * 256 + c2];
    Mt[o * 256 + c2] = gamma[0] * (aw[o * 288 + c2] + 4096.f * s) + (o == c2 ? 1.f : 0.f);
    return;
  }
  __shared__ float qs_l[128], amap_l[128];
  if (t < 128) {
    int b = t >> 5, o = t & 31;
    float s = 4096.f * qb[o];
    for (int c = 0; c < 256; ++c) s += qw[o * 256 + c] * ssum[b * 256 + c];
    qs_l[t] = s;
  }
  __syncthreads();
  if (t < 128) {
    int b = t >> 5, o2 = t & 31;
    float s = 0.f, kt = 0.f;
    for (int o = 0; o < 32; ++o) {
      s += lw[o2 * 64 + 32 + o] * qs_l[b * 32 + o];
      kt += lw[o2 * 64 + o] * kb[o];
    }
    amap_l[t] = 4096.f * (kt + lb[o2]) + s;
  }
  __syncthreads();
  float g = gamma[0];
  for (int i = t; i < 1024; i += 256) {
    int b = i >> 8, c = i & 255;
    float s = ab[c];
    for (int o2 = 0; o2 < 32; ++o2) s += aw[c * 288 + 256 + o2] * amap_l[b * 32 + o2];
    dvec[i] = g * s;
  }
}

// ===== K3: folded conv weights w3 (bf16, 32x32-fragment-major) + cd2 =====
// w3 idx = tap*65536 + cg*4096 + MT*1024 + ks*512 + kh*256 + m*8 + j
//   for oc = MT*32+m, channel cf = cg*32 + ks*16 + kh*8 + j
__global__ void k_w3(const float* __restrict__ cw, const float* __restrict__ Mt,
                     const float* __restrict__ dvec, u16* __restrict__ w3,
                     float* __restrict__ cd2) {
  __shared__ float cwl[8 * 512];
  __shared__ float part[512];
  int blk = blockIdx.x;                 // 144 = 9*16
  int tap = blk >> 4, ocg = blk & 15;
  int tid = threadIdx.x;                // 512 threads
  for (int e = tid; e < 4096; e += 512) {
    int oc = e >> 9, c = e & 511;
    cwl[e] = cw[(size_t)((ocg * 8 + oc) * 512 + c) * 9 + tap];
  }
  __syncthreads();
  int wv = tid >> 6, l = tid & 63;
  int c2 = l * 4;
  f32x4 acc = {0.f, 0.f, 0.f, 0.f};
  for (int c = 0; c < 256; ++c) {
    float wc = cwl[wv * 512 + c];
    f32x4 m = *(const f32x4*)(Mt + c * 256 + c2);
#pragma unroll
    for (int j = 0; j < 4; ++j) acc[j] += wc * m[j];
  }
  int ocf = ocg * 8 + wv;
  int MT = ocf >> 5, m = ocf & 31;
#pragma unroll
  for (int j2 = 0; j2 < 4; ++j2) {
    int cf = c2 + j2;
    int cg = cf >> 5, ks = (cf >> 4) & 1, kh = (cf >> 3) & 1, j = cf & 7;
    w3[tap * 65536 + cg * 4096 + MT * 1024 + ks * 512 + kh * 256 + m * 8 + j] = f2bf(acc[j2]);
    cf = 256 + c2 + j2;
    cg = cf >> 5; ks = (cf >> 4) & 1; kh = (cf >> 3) & 1; j = cf & 7;
    w3[tap * 65536 + cg * 4096 + MT * 1024 + ks * 512 + kh * 256 + m * 8 + j] = f2bf(cwl[wv * 512 + cf]);
  }
  {
    int b = tid >> 7, oc = (tid >> 4) & 7, cp = tid & 15;
    float s = 0.f;
#pragma unroll
    for (int i = 0; i < 16; ++i) s += cwl[oc * 512 + cp * 16 + i] * dvec[b * 256 + cp * 16 + i];
    part[tid] = s;
  }
  __syncthreads();
  if (tid < 32) {
    int b = tid >> 3, oc = tid & 7;
    float s = 0.f;
#pragma unroll
    for (int cp = 0; cp < 16; ++cp) s += part[b * 128 + oc * 16 + cp];
    cd2[(size_t)(b * 128 + ocg * 8 + oc) * 9 + tap] = s;
  }
}

// ===== K4: conv. block=(b,hp,mh): M=64 oc, N=128 (2 rows x 64 px). =====
// 8 waves = 4 K-teams x 2 M-waves (M32 each, N=128 -> acc 4x f32x16).
// A: 9-deep reg batches from global (1KB/wave-load, read ONCE per block).
// B: global_load_lds double-buffer 2x64KB, pre-swizzled xin, 1 barrier/k-step.
__global__ __launch_bounds__(512, 2) void k_conv(const u16* __restrict__ xin,
                                                 const u16* __restrict__ w3,
                                                 const float* __restrict__ cd2,
                                                 float* __restrict__ out) {
  __shared__ u16 lds[65536];            // 128 KB: 2 bufs x 4 teams x 4 rows x 4KB
  int bid = blockIdx.x;
  int b = bid >> 6, hp = (bid >> 1) & 31, mh = bid & 1;
  int h0 = hp * 2;
  int tid = threadIdx.x, l = tid & 63, wv = tid >> 6;
  int team = wv >> 1, mw = wv & 1;
  int ml = l & 31, kh = l >> 5;
  int m32 = mh * 2 + mw;

  // pre-zero border rows in BOTH buffers (they are never staged)
  if (hp == 0 || hp == 31) {
    int row = (hp == 0) ? 0 : 3;
    u16x8 zz;
#pragma unroll
    for (int i = 0; i < 8; ++i) zz[i] = 0;
    for (int i = tid; i < 2048; i += 512) {
      int bu = i >> 10, tm = (i >> 8) & 3, off = i & 255;
      *(u16x8*)(lds + bu * 32768 + tm * 8192 + row * 2048 + off * 8) = zz;
    }
  }

  auto ISSUE = [&](int buf, int k) {
#pragma unroll
    for (int i = 0; i < 8; ++i) {
      int c = wv * 8 + i;               // 0..63
      int tm = c >> 4, row = (c >> 2) & 3, ch = c & 3;
      int grow = h0 - 1 + row;
      if ((unsigned)grow < 64u) {
        const u16* g = xin + ((size_t)(b * 64 + grow) * 16 + tm * 4 + k) * 2048 + ch * 512 + l * 8;
        u16* dl = lds + buf * 32768 + tm * 8192 + row * 2048 + ch * 512;
        gl2lds16(g, dl);
      }
    }
  };

  f32x16 acc[4];
#pragma unroll
  for (int nf = 0; nf < 4; ++nf)
#pragma unroll
    for (int j = 0; j < 16; ++j) acc[nf][j] = 0.f;

  ISSUE(0, 0);
  __syncthreads();

  for (int k = 0; k < 4; ++k) {
    if (k < 3) ISSUE((k + 1) & 1, k + 1);
    const int cg = team * 4 + k;
    const u16* wbase = w3 + cg * 4096 + m32 * 1024 + kh * 256 + ml * 8;
    const u16* Lt = lds + (k & 1) * 32768 + team * 8192;
#pragma unroll
    for (int ks = 0; ks < 2; ++ks) {
      bf16x8 a[9];
#pragma unroll
      for (int t = 0; t < 9; ++t)
        a[t] = *(const bf16x8*)(wbase + t * 65536 + ks * 512);
#pragma unroll
      for (int t = 0; t < 9; ++t) {
        const int dy = t / 3, dx = t % 3;
#pragma unroll
        for (int nf = 0; nf < 4; ++nf) {
          int row = (nf >> 1) + dy;
          int sx = (nf & 1) * 32 + ml + dx - 1;
          bf16x8 bb = bzero();
          if ((unsigned)sx < 64u) {
            int slot = (ks * 2 + kh) ^ ((sx >> 1) & 3);
            bb = *(const bf16x8*)(Lt + row * 2048 + sx * 32 + slot * 8);
          }
          acc[nf] = __builtin_amdgcn_mfma_f32_32x32x16_bf16(a[t], bb, acc[nf], 0, 0, 0);
        }
      }
    }
    __syncthreads();                    // drains this k-step's glds; buf k+1 ready
  }

  // ---- cross-team reduction (regions in first 64KB; buf0 idle since k=2) ----
  float* red = (float*)lds;
  auto DUMP = [&](int rg) {
#pragma unroll
    for (int nf = 0; nf < 4; ++nf)
#pragma unroll
      for (int j4 = 0; j4 < 4; ++j4) {
        f32x4 v = {acc[nf][j4 * 4], acc[nf][j4 * 4 + 1], acc[nf][j4 * 4 + 2], acc[nf][j4 * 4 + 3]};
        *(f32x4*)(red + rg * 8192 + mw * 4096 + nf * 1024 + j4 * 256 + l * 4) = v;
      }
  };
  auto ADD = [&](int rg) {
#pragma unroll
    for (int nf = 0; nf < 4; ++nf)
#pragma unroll
      for (int j4 = 0; j4 < 4; ++j4) {
        f32x4 v = *(const f32x4*)(red + rg * 8192 + mw * 4096 + nf * 1024 + j4 * 256 + l * 4);
#pragma unroll
        for (int jj = 0; jj < 4; ++jj) acc[nf][j4 * 4 + jj] += v[jj];
      }
  };
  if (team >= 2) DUMP(team - 2);
  __syncthreads();
  if (team == 0) ADD(0);
  if (team == 1) ADD(1);
  __syncthreads();
  if (team == 1) DUMP(0);
  __syncthreads();
  if (team == 0) {
    ADD(0);
    // ---- epilogue: border-masked constant correction + store pre-norm y ----
#pragma unroll
    for (int nf = 0; nf < 4; ++nf) {
      int h = h0 + (nf >> 1);
      int px = (nf & 1) * 32 + ml;
      bool dy0v = (h > 0), dy2v = (h < 63);
#pragma unroll
      for (int rg = 0; rg < 4; ++rg) {
#pragma unroll
        for (int j = 0; j < 4; ++j) {
          int oc = mh * 64 + mw * 32 + j + 8 * rg + 4 * kh;
          const float* cd = cd2 + (size_t)(b * 128 + oc) * 9;
          float sAll = 0.f, sL = 0.f, sR = 0.f;
#pragma unroll
          for (int dy = 0; dy < 3; ++dy) {
            bool v = (dy == 1) || (dy == 0 ? dy0v : dy2v);
            if (v) {
              sAll += cd[dy * 3] + cd[dy * 3 + 1] + cd[dy * 3 + 2];
              sL += cd[dy * 3];
              sR += cd[dy * 3 + 2];
            }
          }
          float corr = sAll - (px == 0 ? sL : 0.f) - (px == 63 ? sR : 0.f);
          out[((size_t)(b * 128 + oc)) * 4096 + h * 64 + px] = acc[nf][rg * 4 + j] + corr;
        }
      }
    }
  }
}

// ===== K5: in-place instance norm + relu =====
__global__ void k_norm(float* __restrict__ out) {
  int plane = blockIdx.x;               // 512 = 4*128
  float* p = out + (size_t)plane * 4096;
  int t = threadIdx.x;
  f32x4 v[4];
  float s = 0.f, s2 = 0.f;
#pragma unroll
  for (int i = 0; i < 4; ++i) {
    v[i] = *(const f32x4*)(p + (i * 256 + t) * 4);
#pragma unroll
    for (int k = 0; k < 4; ++k) { s += v[i][k]; s2 += v[i][k] * v[i][k]; }
  }
  s = wave_sum(s); s2 = wave_sum(s2);
  __shared__ float rs[4], rs2[4];
  if ((t & 63) == 0) { rs[t >> 6] = s; rs2[t >> 6] = s2; }
  __syncthreads();
  float S = rs[0] + rs[1] + rs[2] + rs[3];
  float S2 = rs2[0] + rs2[1] + rs2[2] + rs2[3];
  float mean = S * (1.f / 4096.f);
  float var = S2 * (1.f / 4096.f) - mean * mean;
  float inv = rsqrtf(var + 1e-5f);
#pragma unroll
  for (int i = 0; i < 4; ++i) {
    f32x4 o;
#pragma unroll
    for (int k = 0; k < 4; ++k) {
      float y = (v[i][k] - mean) * inv;
      o[k] = y > 0.f ? y : 0.f;
    }
    *(f32x4*)(p + (i * 256 + t) * 4) = o;
  }
}

extern "C" void kernel_launch(void* const* d_in, const int* in_sizes, int n_in,
                              void* d_out, int out_size, void* d_ws, size_t ws_size,
                              hipStream_t stream) {
  const float* src    = (const float*)d_in[0];
  const float* tgt    = (const float*)d_in[1];
  const float* prev   = (const float*)d_in[2];
  const float* key_w  = (const float*)d_in[3];
  const float* key_b  = (const float*)d_in[4];
  const float* qry_w  = (const float*)d_in[5];
  const float* qry_b  = (const float*)d_in[6];
  const float* lin_w  = (const float*)d_in[7];
  const float* lin_b  = (const float*)d_in[8];
  const float* attn_w = (const float*)d_in[9];
  const float* attn_b = (const float*)d_in[10];
  const float* gamma  = (const float*)d_in[11];
  const float* conv_w = (const float*)d_in[12];
  // d_in[13] = conv_b: dropped — per-(b,oc) constant cancels under instance norm.

  char* ws = (char*)d_ws;
  size_t off = 0;
  u16*   xin  = (u16*)(ws + off);  off += 16777216;            // 4*64*64*512 bf16 (pre-swizzled)
  float* ssum = (float*)(ws + off); off += 4096;               // 4*256
  float* dvec = (float*)(ws + off); off += 4096;               // 4*256
  float* Mt   = (float*)(ws + off); off += 262144;             // 256*256
  float* cd2  = (float*)(ws + off); off += 18432;              // 4*128*9
  u16*   w3   = (u16*)(ws + off);  off += 1179648;             // 9*16*4*2*2*256 bf16
  float* out  = (float*)d_out;

  k_xin_plane<<<1280, 256, 0, stream>>>(tgt, prev, src, xin, ssum);
  k_mt_vec<<<257, 256, 0, stream>>>(ssum, qry_w, qry_b, key_w, key_b, lin_w, lin_b,
                                    attn_w, attn_b, gamma, dvec, Mt);
  k_w3<<<144, 512, 0, stream>>>(conv_w, Mt, dvec, w3, cd2);
  k_conv<<<256, 512, 0, stream>>>(xin, w3, cd2, out);
  k_norm<<<512, 256, 0, stream>>>(out);
}